// Round 1
// baseline (395.448 us; speedup 1.0000x reference)
//
#include <hip/hip_runtime.h>
#include <hip/hip_bf16.h>
#include <math.h>

// Problem constants
#define NPTS 65536
#define DIM  256
#define KC   512
#define BM   64     // points per block (main kernel)
#define BKC  64     // codes per LDS chunk
#define STRIDE 260  // padded LDS row stride (dwords): conflict-free + 16B aligned

// d_out layout (floats): [0]=loss, [1..1+16777216)=quantized, [16777217]=perplexity,
// [16777218..+65536)=enc_idx (as float)
#define QOFF  1
#define PIDX  16777217
#define EOFF  16777218

// d_ws layout: wsq f32[512] @0, g f32[512] @512, hist i32[512] @1024, mse f64 @byte 6144

// ---------------- prep: wsq[k] = |w_k|^2, zero hist + mse ----------------
__global__ __launch_bounds__(256) void som_prep(const float* __restrict__ w,
                                                float* __restrict__ wsq,
                                                int* __restrict__ hist,
                                                double* __restrict__ mse_acc)
{
    int k = blockIdx.x * 256 + threadIdx.x;   // grid = 2 blocks -> k in [0,512)
    const float4* r = reinterpret_cast<const float4*>(w + (size_t)k * DIM);
    float s0 = 0.f, s1 = 0.f, s2 = 0.f, s3 = 0.f;
    #pragma unroll 8
    for (int q = 0; q < DIM / 4; ++q) {
        float4 v = r[q];
        s0 = fmaf(v.x, v.x, s0);
        s1 = fmaf(v.y, v.y, s1);
        s2 = fmaf(v.z, v.z, s2);
        s3 = fmaf(v.w, v.w, s3);
    }
    wsq[k] = (s0 + s1) + (s2 + s3);
    hist[k] = 0;
    if (k == 0) *mse_acc = 0.0;
}

// ---------------- main: argmin over codes + quantized write + hist + mse ----------------
__global__ __launch_bounds__(256) void som_main(const float* __restrict__ x,
                                                const float* __restrict__ w,
                                                float* __restrict__ out,
                                                const float* __restrict__ wsq,
                                                int* __restrict__ hist,
                                                double* __restrict__ mse_acc)
{
    __shared__ float xs[BM * STRIDE];     // 66,560 B : x tile, resident all kernel
    __shared__ float wst[BKC * STRIDE];   // 66,560 B : w chunk, re-staged per chunk
    __shared__ float wsq_s[KC];           // 2 KB
    __shared__ float red_d[2 * BM];
    __shared__ int   red_i[2 * BM];
    __shared__ int   bidx_s[BM];
    __shared__ float wsum[4];

    const int tid = threadIdx.x;
    const int ptBlock = blockIdx.x * BM;
    const int lane = tid & 63;
    const int wid = tid >> 6;     // 4 waves
    const int wy = wid & 1;       // point half (0/1 -> rows 0..31 / 32..63)
    const int wx = wid >> 1;      // code half within chunk
    const int lp = lane >> 3;     // point subgroup 0..7
    const int lc = lane & 7;      // code subgroup 0..7

    // stage x tile: 64 pts x 256 floats, coalesced float4
    const float4* xg4 = reinterpret_cast<const float4*>(x);
    #pragma unroll
    for (int it = 0; it < 16; ++it) {
        int idx = it * 256 + tid;            // 0..4095 float4 units
        int p = idx >> 6, q = idx & 63;
        float4 v = xg4[(size_t)(ptBlock + p) * 64 + q];
        *reinterpret_cast<float4*>(&xs[p * STRIDE + q * 4]) = v;
    }
    wsq_s[tid] = wsq[tid];
    wsq_s[256 + tid] = wsq[256 + tid];

    float best[4];
    int   bidx[4];
    #pragma unroll
    for (int i = 0; i < 4; ++i) { best[i] = INFINITY; bidx[i] = 0; }

    const float4* wg4 = reinterpret_cast<const float4*>(w);

    for (int ch = 0; ch < KC / BKC; ++ch) {
        __syncthreads();   // protect wst reuse (and xs on first iter)
        #pragma unroll
        for (int it = 0; it < 16; ++it) {
            int idx = it * 256 + tid;
            int c = idx >> 6, q = idx & 63;
            float4 v = wg4[(size_t)(ch * BKC + c) * 64 + q];
            *reinterpret_cast<float4*>(&wst[c * STRIDE + q * 4]) = v;
        }
        __syncthreads();

        float acc[4][4];
        #pragma unroll
        for (int i = 0; i < 4; ++i)
            #pragma unroll
            for (int j = 0; j < 4; ++j) acc[i][j] = 0.f;

        const float* xbase = &xs[(wy * 32 + lp) * STRIDE];
        const float* wbase = &wst[(wx * 32 + lc) * STRIDE];

        #pragma unroll 2
        for (int d4 = 0; d4 < DIM / 4; ++d4) {
            float4 xv[4], wv[4];
            #pragma unroll
            for (int i = 0; i < 4; ++i)
                xv[i] = *reinterpret_cast<const float4*>(xbase + i * 8 * STRIDE + d4 * 4);
            #pragma unroll
            for (int j = 0; j < 4; ++j)
                wv[j] = *reinterpret_cast<const float4*>(wbase + j * 8 * STRIDE + d4 * 4);
            #pragma unroll
            for (int i = 0; i < 4; ++i)
                #pragma unroll
                for (int j = 0; j < 4; ++j) {
                    acc[i][j] = fmaf(xv[i].x, wv[j].x, acc[i][j]);
                    acc[i][j] = fmaf(xv[i].y, wv[j].y, acc[i][j]);
                    acc[i][j] = fmaf(xv[i].z, wv[j].z, acc[i][j]);
                    acc[i][j] = fmaf(xv[i].w, wv[j].w, acc[i][j]);
                }
        }

        // compare: dist = wsq[c] - 2*dot  (|x|^2 dropped: constant per point)
        #pragma unroll
        for (int i = 0; i < 4; ++i)
            #pragma unroll
            for (int j = 0; j < 4; ++j) {
                int c = ch * BKC + wx * 32 + j * 8 + lc;
                float dist = wsq_s[c] - 2.f * acc[i][j];
                if (dist < best[i]) { best[i] = dist; bidx[i] = c; }  // earlier c kept on tie
            }
    }

    // reduce across code-subgroup lanes (lc = low 3 bits of lane)
    #pragma unroll
    for (int i = 0; i < 4; ++i) {
        #pragma unroll
        for (int m = 1; m <= 4; m <<= 1) {
            float od = __shfl_xor(best[i], m, 64);
            int   oi = __shfl_xor(bidx[i], m, 64);
            if (od < best[i] || (od == best[i] && oi < bidx[i])) { best[i] = od; bidx[i] = oi; }
        }
    }
    if (lc == 0) {
        #pragma unroll
        for (int i = 0; i < 4; ++i) {
            int p = wy * 32 + i * 8 + lp;
            red_d[wx * BM + p] = best[i];
            red_i[wx * BM + p] = bidx[i];
        }
    }
    __syncthreads();

    if (tid < BM) {
        int p = tid;
        float d0 = red_d[p];       int i0 = red_i[p];
        float d1 = red_d[BM + p];  int i1 = red_i[BM + p];
        int sel = (d1 < d0 || (d1 == d0 && i1 < i0)) ? i1 : i0;
        bidx_s[p] = sel;
        out[EOFF + ptBlock + p] = (float)sel;
        atomicAdd(&hist[sel], 1);
    }
    __syncthreads();

    // quantized = w[sel]; accumulate sum of (q-x)^2
    float lsum = 0.f;
    for (int p = 0; p < BM; ++p) {
        int c = bidx_s[p];
        float qv = w[(size_t)c * DIM + tid];       // coalesced row (L2-hot)
        float xv = xs[p * STRIDE + tid];
        out[QOFF + (size_t)(ptBlock + p) * DIM + tid] = qv;
        float dd = qv - xv;
        lsum = fmaf(dd, dd, lsum);
    }
    #pragma unroll
    for (int m = 32; m; m >>= 1) lsum += __shfl_xor(lsum, m, 64);
    if (lane == 0) wsum[wid] = lsum;
    __syncthreads();
    if (tid == 0)
        atomicAdd(mse_acc, (double)((wsum[0] + wsum[1]) + (wsum[2] + wsum[3])));
}

// ---------------- g[j] = sum_k bmat[j,k] * (wsq[k] + wsq[j] - 2 w_j.w_k) ----------------
__global__ __launch_bounds__(256) void som_g(const float* __restrict__ w,
                                             const float* __restrict__ bmat,
                                             const float* __restrict__ wsq,
                                             float* __restrict__ g)
{
    __shared__ float wj[DIM];
    __shared__ float psum[4];
    const int j = blockIdx.x;
    const int tid = threadIdx.x;
    wj[tid] = w[(size_t)j * DIM + tid];
    __syncthreads();
    const float wsqj = wsq[j];
    float sum = 0.f;
    for (int k = tid; k < KC; k += 256) {
        const float* wk = &w[(size_t)k * DIM];
        float d0 = 0.f, d1 = 0.f, d2 = 0.f, d3 = 0.f;
        #pragma unroll 4
        for (int d = 0; d < DIM; d += 4) {
            d0 = fmaf(wj[d + 0], wk[d + 0], d0);
            d1 = fmaf(wj[d + 1], wk[d + 1], d1);
            d2 = fmaf(wj[d + 2], wk[d + 2], d2);
            d3 = fmaf(wj[d + 3], wk[d + 3], d3);
        }
        float dot = (d0 + d1) + (d2 + d3);
        float t = wsq[k] + wsqj - 2.f * dot;
        sum = fmaf(bmat[(size_t)j * KC + k], t, sum);
    }
    #pragma unroll
    for (int m = 32; m; m >>= 1) sum += __shfl_xor(sum, m, 64);
    int lane = tid & 63, wid = tid >> 6;
    if (lane == 0) psum[wid] = sum;
    __syncthreads();
    if (tid == 0) g[j] = (psum[0] + psum[1]) + (psum[2] + psum[3]);
}

// ---------------- final: perplexity + loss ----------------
__global__ __launch_bounds__(512) void som_final(const int* __restrict__ hist,
                                                 const float* __restrict__ g,
                                                 const double* __restrict__ mse_acc,
                                                 float* __restrict__ out)
{
    __shared__ float e_part[8], k_part[8];
    const int tid = threadIdx.x;
    int cnt = hist[tid];
    float p = (float)cnt / (float)NPTS;
    float ent = -p * logf(p + 1e-10f);
    float koh = (float)cnt * g[tid];
    #pragma unroll
    for (int m = 32; m; m >>= 1) {
        ent += __shfl_xor(ent, m, 64);
        koh += __shfl_xor(koh, m, 64);
    }
    int lane = tid & 63, wid = tid >> 6;
    if (lane == 0) { e_part[wid] = ent; k_part[wid] = koh; }
    __syncthreads();
    if (tid == 0) {
        float es = 0.f, ks = 0.f;
        #pragma unroll
        for (int i = 0; i < 8; ++i) { es += e_part[i]; ks += k_part[i]; }
        float mse = (float)(*mse_acc / (double)(NPTS * (size_t)DIM));
        out[0] = fmaf(1.25f, mse, ks / (float)NPTS);
        out[PIDX] = expf(es);
    }
}

extern "C" void kernel_launch(void* const* d_in, const int* in_sizes, int n_in,
                              void* d_out, int out_size, void* d_ws, size_t ws_size,
                              hipStream_t stream) {
    const float* x    = (const float*)d_in[0];
    const float* w    = (const float*)d_in[1];
    const float* bmat = (const float*)d_in[2];
    float* out = (float*)d_out;

    float*  wsq  = (float*)d_ws;
    float*  g    = wsq + 512;
    int*    hist = (int*)d_ws + 1024;
    double* mse  = (double*)((char*)d_ws + 6144);

    som_prep <<<2, 256, 0, stream>>>(w, wsq, hist, mse);
    som_main <<<NPTS / BM, 256, 0, stream>>>(x, w, out, wsq, hist, mse);
    som_g    <<<KC, 256, 0, stream>>>(w, bmat, wsq, g);
    som_final<<<1, KC, 0, stream>>>(hist, g, mse, out);
}

// Round 3
// 346.292 us; speedup vs baseline: 1.1419x; 1.1419x over previous
//
#include <hip/hip_runtime.h>
#include <hip/hip_bf16.h>
#include <math.h>

// Problem constants
#define NPTS 65536
#define DIM  256
#define KC   512

// som_main geometry
#define BM   256    // points per block
#define NBLK (NPTS / BM)          // 256 blocks = 1 per CU
#define DSL  64     // D slice (floats) staged in LDS at a time
#define LSTR 68     // LDS row stride in dwords: 272 B = 16B-aligned, bank shift 4/row

// d_out layout (floats): [0]=loss, [1..1+16777216)=quantized, [16777217]=perplexity,
// [16777218..+65536)=enc_idx (as float)
#define QOFF  1
#define PIDX  16777217
#define EOFF  16777218

// d_ws layout: wsq f32[512] @0, g f32[512] @512, hist i32[512] @1024, mse f64 @byte 6144

// ---------------- prep: wsq[k] = |w_k|^2, zero hist + mse ----------------
__global__ __launch_bounds__(256) void som_prep(const float* __restrict__ w,
                                                float* __restrict__ wsq,
                                                int* __restrict__ hist,
                                                double* __restrict__ mse_acc)
{
    int k = blockIdx.x * 256 + threadIdx.x;   // grid = 2 blocks -> k in [0,512)
    const float4* r = reinterpret_cast<const float4*>(w + (size_t)k * DIM);
    float s0 = 0.f, s1 = 0.f, s2 = 0.f, s3 = 0.f;
    #pragma unroll 8
    for (int q = 0; q < DIM / 4; ++q) {
        float4 v = r[q];
        s0 = fmaf(v.x, v.x, s0);
        s1 = fmaf(v.y, v.y, s1);
        s2 = fmaf(v.z, v.z, s2);
        s3 = fmaf(v.w, v.w, s3);
    }
    wsq[k] = (s0 + s1) + (s2 + s3);
    hist[k] = 0;
    if (k == 0) *mse_acc = 0.0;
}

// ---------------- main: argmin + quantized write + hist + mse ----------------
// 512 threads = 8 waves arranged 2 (point-groups) x 4 (code-groups).
// Wave tile: 128 pts x 64 codes. Lane tile: 16 pts x 8 codes.
// Code chunks of 256 (cch), D slices of 64 (dch) staged in LDS.
__global__ __launch_bounds__(512, 2) void som_main(const float* __restrict__ x,
                                                   const float* __restrict__ w,
                                                   float* __restrict__ out,
                                                   const float* __restrict__ wsq,
                                                   int* __restrict__ hist,
                                                   double* __restrict__ mse_acc)
{
    __shared__ float xs[BM * LSTR];        // 69,632 B : x tile D-slice
    __shared__ float wst[256 * LSTR];      // 69,632 B : w chunk D-slice
    __shared__ float wsq_s[KC];            // 2 KB
    __shared__ float xsq_part[512];        // 2 KB : per (pt, half) |x|^2 partials
    __shared__ float red_d[4 * BM];        // 4 KB
    __shared__ int   red_i[4 * BM];        // 4 KB
    __shared__ int   bidx_s[BM];           // 1 KB
    __shared__ float wsum[4];

    const int tid  = threadIdx.x;
    const int ptBlock = blockIdx.x * BM;
    const int lane = tid & 63;
    const int wid  = tid >> 6;    // 0..7
    const int wgp  = wid >> 2;    // point group 0..1  (128 pts each)
    const int wgc  = wid & 3;     // code group 0..3   (64 codes each)
    const int lp   = lane >> 3;   // 0..7 point sub
    const int lc   = lane & 7;    // 0..7 code sub

    const float4* xg4 = reinterpret_cast<const float4*>(x);
    const float4* wg4 = reinterpret_cast<const float4*>(w);

    wsq_s[tid] = wsq[tid];        // 512 threads cover K=512

    float best[16];
    int   bidx[16];
    #pragma unroll
    for (int i = 0; i < 16; ++i) { best[i] = INFINITY; bidx[i] = 0; }

    float xacc = 0.f;             // |x|^2 partial for (pt=tid>>1, half=tid&1)

    const float* xbase = &xs[(wgp * 128 + lp) * LSTR];
    const float* wbase = &wst[(wgc * 64 + lc) * LSTR];   // FIXED: include code-group offset

    for (int cch = 0; cch < 2; ++cch) {
        float acc[16][8];
        #pragma unroll
        for (int i = 0; i < 16; ++i)
            #pragma unroll
            for (int j = 0; j < 8; ++j) acc[i][j] = 0.f;

        for (int dch = 0; dch < 4; ++dch) {
            __syncthreads();      // readers of previous slice done
            // stage x slice: 256 rows x 16 float4
            #pragma unroll
            for (int it = 0; it < 8; ++it) {
                int idx = it * 512 + tid;          // 0..4095
                int row = idx >> 4, c4 = idx & 15;
                float4 v = xg4[(size_t)(ptBlock + row) * 64 + dch * 16 + c4];
                *reinterpret_cast<float4*>(&xs[row * LSTR + c4 * 4]) = v;
            }
            // stage w slice: 256 rows x 16 float4
            #pragma unroll
            for (int it = 0; it < 8; ++it) {
                int idx = it * 512 + tid;
                int row = idx >> 4, c4 = idx & 15;
                float4 v = wg4[(size_t)(cch * 256 + row) * 64 + dch * 16 + c4];
                *reinterpret_cast<float4*>(&wst[row * LSTR + c4 * 4]) = v;
            }
            __syncthreads();      // slice ready

            if (cch == 0) {       // accumulate |x|^2 from LDS (once per point)
                int pt = tid >> 1, half = tid & 1;
                const float* xr = &xs[pt * LSTR + half * 32];
                #pragma unroll
                for (int k = 0; k < 8; ++k) {
                    float4 v = *reinterpret_cast<const float4*>(xr + k * 4);
                    xacc = fmaf(v.x, v.x, xacc);
                    xacc = fmaf(v.y, v.y, xacc);
                    xacc = fmaf(v.z, v.z, xacc);
                    xacc = fmaf(v.w, v.w, xacc);
                }
            }

            // main FMA loop over this D slice
            for (int d4 = 0; d4 < DSL / 4; ++d4) {
                float4 wv[8];
                #pragma unroll
                for (int j = 0; j < 8; ++j)
                    wv[j] = *reinterpret_cast<const float4*>(wbase + j * 8 * LSTR + d4 * 4);
                #pragma unroll
                for (int i = 0; i < 16; ++i) {
                    float4 xv = *reinterpret_cast<const float4*>(xbase + i * 8 * LSTR + d4 * 4);
                    #pragma unroll
                    for (int j = 0; j < 8; ++j) {
                        acc[i][j] = fmaf(xv.x, wv[j].x, acc[i][j]);
                        acc[i][j] = fmaf(xv.y, wv[j].y, acc[i][j]);
                        acc[i][j] = fmaf(xv.z, wv[j].z, acc[i][j]);
                        acc[i][j] = fmaf(xv.w, wv[j].w, acc[i][j]);
                    }
                }
            }
        }

        // full-D dots done for this code chunk: dist = wsq[c] - 2*dot
        #pragma unroll
        for (int i = 0; i < 16; ++i)
            #pragma unroll
            for (int j = 0; j < 8; ++j) {
                int c = cch * 256 + wgc * 64 + j * 8 + lc;
                float dist = wsq_s[c] - 2.f * acc[i][j];
                if (dist < best[i]) { best[i] = dist; bidx[i] = c; }
            }
    }

    // store |x|^2 partials
    xsq_part[tid] = xacc;

    // reduce across lc lanes (low 3 bits)
    #pragma unroll
    for (int i = 0; i < 16; ++i) {
        #pragma unroll
        for (int m = 1; m <= 4; m <<= 1) {
            float od = __shfl_xor(best[i], m, 64);
            int   oi = __shfl_xor(bidx[i], m, 64);
            if (od < best[i] || (od == best[i] && oi < bidx[i])) { best[i] = od; bidx[i] = oi; }
        }
    }
    if (lc == 0) {
        #pragma unroll
        for (int i = 0; i < 16; ++i) {
            int p = wgp * 128 + i * 8 + lp;       // 0..255
            red_d[wgc * BM + p] = best[i];
            red_i[wgc * BM + p] = bidx[i];
        }
    }
    __syncthreads();

    // final per-point reduce over 4 code groups + mse
    if (tid < BM) {
        int p = tid;
        float bd = red_d[p];  int bi = red_i[p];
        #pragma unroll
        for (int g = 1; g < 4; ++g) {
            float d = red_d[g * BM + p];  int i2 = red_i[g * BM + p];
            if (d < bd || (d == bd && i2 < bi)) { bd = d; bi = i2; }
        }
        bidx_s[p] = bi;
        out[EOFF + ptBlock + p] = (float)bi;
        atomicAdd(&hist[bi], 1);

        float msum = xsq_part[2 * p] + xsq_part[2 * p + 1] + bd;  // |x-w|^2 for this point
        #pragma unroll
        for (int m = 32; m; m >>= 1) msum += __shfl_xor(msum, m, 64);
        if (lane == 0) wsum[wid] = msum;
    }
    __syncthreads();
    if (tid == 0)
        atomicAdd(mse_acc, (double)((wsum[0] + wsum[1]) + (wsum[2] + wsum[3])));

    // quantized = w[sel] write: 2 rows per iter, fully coalesced dword stores
    {
        int d = tid & 255;
        int ph = tid >> 8;        // 0..1
        for (int pp = 0; pp < 128; ++pp) {
            int p = pp * 2 + ph;
            int c = bidx_s[p];
            float qv = w[(size_t)c * DIM + d];
            out[QOFF + (size_t)(ptBlock + p) * DIM + d] = qv;
        }
    }
}

// ---------------- g[j] = sum_k bmat[j,k] * (wsq[k] + wsq[j] - 2 w_j.w_k) ----------------
__global__ __launch_bounds__(256) void som_g(const float* __restrict__ w,
                                             const float* __restrict__ bmat,
                                             const float* __restrict__ wsq,
                                             float* __restrict__ g)
{
    __shared__ float wj[DIM];
    __shared__ float psum[4];
    const int j = blockIdx.x;
    const int tid = threadIdx.x;
    wj[tid] = w[(size_t)j * DIM + tid];
    __syncthreads();
    const float wsqj = wsq[j];
    float sum = 0.f;
    for (int k = tid; k < KC; k += 256) {
        const float* wk = &w[(size_t)k * DIM];
        float d0 = 0.f, d1 = 0.f, d2 = 0.f, d3 = 0.f;
        #pragma unroll 4
        for (int d = 0; d < DIM; d += 4) {
            d0 = fmaf(wj[d + 0], wk[d + 0], d0);
            d1 = fmaf(wj[d + 1], wk[d + 1], d1);
            d2 = fmaf(wj[d + 2], wk[d + 2], d2);
            d3 = fmaf(wj[d + 3], wk[d + 3], d3);
        }
        float dot = (d0 + d1) + (d2 + d3);
        float t = wsq[k] + wsqj - 2.f * dot;
        sum = fmaf(bmat[(size_t)j * KC + k], t, sum);
    }
    #pragma unroll
    for (int m = 32; m; m >>= 1) sum += __shfl_xor(sum, m, 64);
    int lane = tid & 63, wid = tid >> 6;
    if (lane == 0) psum[wid] = sum;
    __syncthreads();
    if (tid == 0) g[j] = (psum[0] + psum[1]) + (psum[2] + psum[3]);
}

// ---------------- final: perplexity + loss ----------------
__global__ __launch_bounds__(512) void som_final(const int* __restrict__ hist,
                                                 const float* __restrict__ g,
                                                 const double* __restrict__ mse_acc,
                                                 float* __restrict__ out)
{
    __shared__ float e_part[8], k_part[8];
    const int tid = threadIdx.x;
    int cnt = hist[tid];
    float p = (float)cnt / (float)NPTS;
    float ent = -p * logf(p + 1e-10f);
    float koh = (float)cnt * g[tid];
    #pragma unroll
    for (int m = 32; m; m >>= 1) {
        ent += __shfl_xor(ent, m, 64);
        koh += __shfl_xor(koh, m, 64);
    }
    int lane = tid & 63, wid = tid >> 6;
    if (lane == 0) { e_part[wid] = ent; k_part[wid] = koh; }
    __syncthreads();
    if (tid == 0) {
        float es = 0.f, ks = 0.f;
        #pragma unroll
        for (int i = 0; i < 8; ++i) { es += e_part[i]; ks += k_part[i]; }
        float mse = (float)(*mse_acc / (double)(NPTS * (size_t)DIM));
        out[0] = fmaf(1.25f, mse, ks / (float)NPTS);
        out[PIDX] = expf(es);
    }
}

extern "C" void kernel_launch(void* const* d_in, const int* in_sizes, int n_in,
                              void* d_out, int out_size, void* d_ws, size_t ws_size,
                              hipStream_t stream) {
    const float* x    = (const float*)d_in[0];
    const float* w    = (const float*)d_in[1];
    const float* bmat = (const float*)d_in[2];
    float* out = (float*)d_out;

    float*  wsq  = (float*)d_ws;
    float*  g    = wsq + 512;
    int*    hist = (int*)d_ws + 1024;
    double* mse  = (double*)((char*)d_ws + 6144);

    som_prep <<<2, 256, 0, stream>>>(w, wsq, hist, mse);
    som_main <<<NBLK, 512, 0, stream>>>(x, w, out, wsq, hist, mse);
    som_g    <<<KC, 256, 0, stream>>>(w, bmat, wsq, g);
    som_final<<<1, KC, 0, stream>>>(hist, g, mse, out);
}